// Round 1
// baseline (335.109 us; speedup 1.0000x reference)
//
#include <hip/hip_runtime.h>

// HadamardClassifier: out = -scale * l2norm(x) @ H + bias
// H = Sylvester-Hadamard(16384)[:2048, :14951]  =>  H[i,j] = (-1)^popcount(i & j),
// and since i < 2^11, H[i,j] depends only on (j & 2047):
//   out[b, j] = (-scale / ||x_b||) * FWHT_2048(x_b)[j & 2047] + bias[j]
// One wave (64 lanes) per row; element e = r*64 + lane held in v[r], r=0..31.

#define IN_DIM 2048
#define OUT_DIM 14951
#define BATCH 4096

__global__ __launch_bounds__(256) void HadamardClassifier_74586402062910_kernel(
    const float* __restrict__ x,
    const float* __restrict__ scale,
    const float* __restrict__ bias,
    float* __restrict__ out)
{
    const int lane = threadIdx.x & 63;
    const int wave = threadIdx.x >> 6;
    const int row  = blockIdx.x * 4 + wave;   // grid = BATCH/4 blocks exactly

    const float* __restrict__ xr = x + (size_t)row * IN_DIM;

    // ---- load row, layout e = r*64 + lane (coalesced 256B per load) ----
    float v[32];
    float ss = 0.f;
    #pragma unroll
    for (int r = 0; r < 32; ++r) {
        float t = xr[r * 64 + lane];
        v[r] = t;
        ss = fmaf(t, t, ss);
    }

    // ---- wave-wide sum of squares (butterfly: every lane gets the total) ----
    #pragma unroll
    for (int s = 1; s < 64; s <<= 1)
        ss += __shfl_xor(ss, s, 64);

    const float norm   = sqrtf(fmaxf(ss, 1e-12f));   // tf.l2_normalize EPS
    const float factor = -scale[0] / norm;           // fold sign+scale+norm

    // ---- FWHT, cross-lane stages (bits 0..5 of e are the lane bits) ----
    #pragma unroll
    for (int s = 1; s < 64; s <<= 1) {
        const bool hi = (lane & s) != 0;
        #pragma unroll
        for (int r = 0; r < 32; ++r) {
            float t = __shfl_xor(v[r], s, 64);
            v[r] = hi ? (t - v[r]) : (v[r] + t);
        }
    }

    // ---- FWHT, in-register stages (bits of r), fully static indexing ----
    #pragma unroll
    for (int sr = 1; sr < 32; sr <<= 1) {
        #pragma unroll
        for (int r = 0; r < 32; ++r) {
            if ((r & sr) == 0) {
                const float a = v[r], b = v[r | sr];
                v[r]      = a + b;
                v[r | sr] = a - b;
            }
        }
    }

    #pragma unroll
    for (int r = 0; r < 32; ++r) v[r] *= factor;

    // ---- write out[b, j] = v[(j>>6) & 31] + bias[j], j = m*64 + lane ----
    // 14951 = 233 full 64-wide blocks + 39 remainder; 233 = 7*32 + 9.
    float* __restrict__ orow = out + (size_t)row * OUT_DIM;

    for (int g = 0; g < 7; ++g) {               // m = g*32 + mm, r = m&31 = mm
        const int mbase = g * 32;
        #pragma unroll
        for (int mm = 0; mm < 32; ++mm) {
            const int j = (mbase + mm) * 64 + lane;
            orow[j] = v[mm] + bias[j];
        }
    }
    #pragma unroll
    for (int mm = 0; mm < 9; ++mm) {            // m = 224..232, r = mm
        const int j = (224 + mm) * 64 + lane;
        orow[j] = v[mm] + bias[j];
    }
    if (lane < 39) {                            // m = 233, r = 233&31 = 9
        const int j = 233 * 64 + lane;
        orow[j] = v[9] + bias[j];
    }
}

extern "C" void kernel_launch(void* const* d_in, const int* in_sizes, int n_in,
                              void* d_out, int out_size, void* d_ws, size_t ws_size,
                              hipStream_t stream) {
    const float* x     = (const float*)d_in[0];
    // d_in[1] = hadamard: structure exploited analytically, not read.
    const float* scale = (const float*)d_in[2];
    const float* bias  = (const float*)d_in[3];
    float* out = (float*)d_out;

    dim3 grid(BATCH / 4);   // 1024 blocks, 4 waves = 4 rows per block
    dim3 block(256);
    HadamardClassifier_74586402062910_kernel<<<grid, block, 0, stream>>>(x, scale, bias, out);
}